// Round 1
// baseline (232.821 us; speedup 1.0000x reference)
//
#include <hip/hip_runtime.h>
#include <hip/hip_cooperative_groups.h>
#include <cmath>

namespace cg = cooperative_groups;

#define BINS 10
#define EDGE_TOP (1.0f + 1e-6f)
#define BLK 256
#define CHUNK 16   // float4s held in registers per thread in the fused kernel

// Precise-exp slow path, outlined so the 64x-unrolled fused kernel doesn't
// inline 64 copies of the f64 exp blob (I-cache is 32 KiB). Hazard rate is
// ~2e-4/element, so the call overhead is irrelevant.
__device__ __noinline__ float ghm_g_precise(float p) {
    double ed = exp(-(double)p);
    return fabsf((float)ed - 1.0f);
}

// Classify via native exp (2 instr). Near-boundary values (within 1e-4 of a
// bin edge in g*10 space, >> the ~8e-6 fast-exp error) are recomputed with
// double-precision exp so the fp32 result matches numpy's fp32 exp.
// This hazard machinery is proven: absmax 7.8e-3 vs threshold 0.385 (R1/R2).
__device__ __forceinline__ void ghm_classify_fast(float p, int& bin, bool& lt_top) {
    float ef  = __expf(-p);
    float g   = fabsf(ef - 1.0f);
    float g10 = g * 10.0f;
    int   b   = (int)g10;          // g >= 0, trunc == floor (saturating cvt)
    float fb  = (float)b;
    bool hazard = (g10 - fb < 1e-4f) || (fb + 1.0f - g10 < 1e-4f) ||
                  (fabsf(g - EDGE_TOP) < 4e-6f);
    if (hazard) {
        g   = ghm_g_precise(p);
        g10 = g * 10.0f;
        b   = (int)g10;
    }
    bin    = (b < 9) ? b : 9;
    lt_top = (g < EDGE_TOP);
}

// Histogram state: two u64s with 5 x 12-bit fields each (bins 0-4 in h0,
// 5-9 in h1). 12-bit fields tolerate up to 4095 elems/thread -> no overflow
// constraint on grid sizing (the old 6-bit scheme capped at 63).
__device__ __forceinline__ void ghm_acc(unsigned long long& h0,
                                        unsigned long long& h1,
                                        bool ib, int bin) {
    int bl = (bin < 5) ? bin : (bin - 5);
    unsigned long long inc = ib ? (1ull << (bl * 12)) : 0ull;
    h0 += (bin < 5) ? inc : 0ull;
    h1 += (bin < 5) ? 0ull : inc;
}

// Unpack per-thread fields, wave shuffle-reduce, LDS combine, 11 global
// atomics per block (the R1 ending — proven cheap).
__device__ __forceinline__ void ghm_reduce_commit(
    unsigned long long h0, unsigned long long h1, unsigned int vcnt,
    unsigned int* __restrict__ cnt)
{
    unsigned int vals[BINS + 1];
#pragma unroll
    for (int b = 0; b < 5; ++b) {
        vals[b]     = (unsigned int)((h0 >> (12 * b)) & 4095ull);
        vals[b + 5] = (unsigned int)((h1 >> (12 * b)) & 4095ull);
    }
    vals[BINS] = vcnt;

    __shared__ unsigned int sc[BINS + 1];
    if (threadIdx.x < BINS + 1) sc[threadIdx.x] = 0u;
    __syncthreads();
#pragma unroll
    for (int b = 0; b <= BINS; ++b) {
        unsigned int v = vals[b];
#pragma unroll
        for (int off = 32; off > 0; off >>= 1)
            v += __shfl_down(v, off, 64);
        if ((threadIdx.x & 63) == 0) atomicAdd(&sc[b], v);
    }
    __syncthreads();
    if (threadIdx.x < BINS + 1) atomicAdd(&cnt[threadIdx.x], sc[threadIdx.x]);
}

// Wave-cooperative weights: lane b<10 holds w[b]; lane 15 holds 0.0 so
// sentinel code 15 yields weight 0 via ds_bpermute. Counter loads are
// agent-scope atomics: after grid.sync() the counters were produced by
// blocks on other XCDs (per-XCD L2s are NOT coherent for plain loads).
__device__ __forceinline__ int ghm_wave_weights(const unsigned int* __restrict__ cnt) {
    const int lane = threadIdx.x & 63;
    unsigned int cv = __hip_atomic_load(&cnt[lane < 10 ? lane : 10],
                                        __ATOMIC_RELAXED, __HIP_MEMORY_SCOPE_AGENT);
    float totf = fmaxf((float)__shfl((int)cv, 10, 64), 1.0f);
    unsigned long long nem = __ballot(lane < 10 && cv > 0u);
    int nne = __popcll(nem);
    float nf = fmaxf((float)nne, 1.0f);
    float wfl = 0.0f;
    if (lane < 10 && cv > 0u) {
        wfl = totf / (float)cv;      // tot / counts[b]
        if (nne > 0) wfl = wfl / nf; // / n_nonempty  (reference op order)
    }
    return __float_as_int(wfl);
}

// Fused single-pass kernel (cooperative). Phase 1: load pred (kept in regs)
// + lw, classify, per-thread histogram, block-reduce, global atomics.
// grid.sync(). Phase 2: weights from counters, out = w * pred from regs.
// Traffic = 196.6 MB (the minimum): no pred re-read, no codes round-trip.
__global__ __launch_bounds__(BLK, 4) void ghm_fused(
    const float* __restrict__ pred, const float* __restrict__ lw,
    unsigned int* __restrict__ cnt, float* __restrict__ out, int n)
{
    const int tid = blockIdx.x * BLK + threadIdx.x;
    const int S   = gridDim.x * BLK;
    const int n4  = n >> 2;
    const float4* p4 = (const float4*)pred;
    const float4* w4 = (const float4*)lw;

    float4 P[CHUNK];                 // 64 VGPRs, live across grid.sync()
    unsigned int code[CHUNK / 2];    // 4 bits/elem, 16 bits per float4
    unsigned long long h0 = 0ull, h1 = 0ull;
    unsigned int vcnt = 0;

    // Issue all 16 pred loads back-to-back (clamped addr, no branches) for
    // maximum MLP; host guarantees n4 > 0 on this path.
#pragma unroll
    for (int j = 0; j < CHUNK; ++j) {
        int idx = tid + j * S;
        int ci  = idx < n4 ? idx : (n4 - 1);
        P[j] = p4[ci];
    }
#pragma unroll
    for (int jc = 0; jc < CHUNK / 2; ++jc) code[jc] = 0u;

#pragma unroll
    for (int g = 0; g < CHUNK / 4; ++g) {
        float4 W[4];
#pragma unroll
        for (int jj = 0; jj < 4; ++jj) {
            int idx = tid + (g * 4 + jj) * S;
            int ci  = idx < n4 ? idx : (n4 - 1);
            W[jj] = w4[ci];
        }
#pragma unroll
        for (int jj = 0; jj < 4; ++jj) {
            const int j = g * 4 + jj;
            const int idx = tid + j * S;
            const bool inr = idx < n4;
            float ps_[4] = {P[j].x, P[j].y, P[j].z, P[j].w};
            float ws_[4] = {W[jj].x, W[jj].y, W[jj].z, W[jj].w};
#pragma unroll
            for (int k = 0; k < 4; ++k) {
                bool valid = inr && (ws_[k] > 0.0f);
                vcnt += valid ? 1u : 0u;
                int bin; bool lt;
                ghm_classify_fast(ps_[k], bin, lt);
                bool ib = valid && lt;
                ghm_acc(h0, h1, ib, bin);
                unsigned int nib = ib ? (unsigned int)bin : 15u;
                const int e = j * 4 + k;           // compile-time after unroll
                code[e >> 3] |= nib << ((e & 7) * 4);
            }
        }
    }
    // scalar tail (n % 4): counted by thread 0 (12-bit fields have headroom)
    if (tid == 0) {
        for (int j2 = n4 << 2; j2 < n; ++j2) {
            bool valid = lw[j2] > 0.0f;
            vcnt += valid ? 1u : 0u;
            int bin; bool lt;
            ghm_classify_fast(pred[j2], bin, lt);
            ghm_acc(h0, h1, valid && lt, bin);
        }
    }

    ghm_reduce_commit(h0, h1, vcnt, cnt);

    cg::this_grid().sync();

    const int wfi = ghm_wave_weights(cnt);

    float4* o4 = (float4*)out;
#pragma unroll
    for (int j = 0; j < CHUNK; ++j) {
        int idx = tid + j * S;
        unsigned int cj = code[j >> 1] >> ((j & 1) * 16);
        // bpermute executed by ALL lanes (source lanes 0-9/15 must be active);
        // only the store is predicated.
        float4 O;
        O.x = __int_as_float(__builtin_amdgcn_ds_bpermute(
                  (int)((cj & 15u) << 2), wfi)) * P[j].x;
        O.y = __int_as_float(__builtin_amdgcn_ds_bpermute(
                  (int)(((cj >> 4) & 15u) << 2), wfi)) * P[j].y;
        O.z = __int_as_float(__builtin_amdgcn_ds_bpermute(
                  (int)(((cj >> 8) & 15u) << 2), wfi)) * P[j].z;
        O.w = __int_as_float(__builtin_amdgcn_ds_bpermute(
                  (int)(((cj >> 12) & 15u) << 2), wfi)) * P[j].w;
        if (idx < n4) o4[idx] = O;
    }
    // scalar tail: lone thread -> no cross-lane ops (bpermute from inactive
    // lanes is undefined); compute weights arithmetically from the counters.
    if (tid == 0 && (n & 3)) {
        unsigned int c[BINS + 1];
        for (int b = 0; b <= BINS; ++b)
            c[b] = __hip_atomic_load(&cnt[b], __ATOMIC_RELAXED,
                                     __HIP_MEMORY_SCOPE_AGENT);
        float totf = fmaxf((float)c[BINS], 1.0f);
        int nne = 0;
        for (int b = 0; b < BINS; ++b) nne += (c[b] > 0u) ? 1 : 0;
        float nf = fmaxf((float)nne, 1.0f);
        for (int j2 = n4 << 2; j2 < n; ++j2) {
            int bin; bool lt;
            ghm_classify_fast(pred[j2], bin, lt);
            bool ib = (lw[j2] > 0.0f) && lt;
            float wt = 0.0f;
            if (ib && c[bin] > 0u) {
                wt = totf / (float)c[bin];
                if (nne > 0) wt /= nf;
            }
            out[j2] = wt * pred[j2];
        }
    }
}

// ---------- fallback two-pass path (cooperative launch unavailable) ----------

__global__ __launch_bounds__(BLK) void ghm_hist(
    const float* __restrict__ pred, const float* __restrict__ lw,
    unsigned int* __restrict__ cnt, int n)
{
    unsigned long long h0 = 0ull, h1 = 0ull;
    unsigned int vcnt = 0;
    const int tid = blockIdx.x * BLK + threadIdx.x;
    const int S   = gridDim.x * BLK;
    const int n4  = n >> 2;
    const float4* p4 = (const float4*)pred;
    const float4* w4 = (const float4*)lw;

    for (int i = tid; i < n4; i += S) {
        float4 P = p4[i];
        float4 W = w4[i];
        float ps_[4] = {P.x, P.y, P.z, P.w};
        float ws_[4] = {W.x, W.y, W.z, W.w};
#pragma unroll
        for (int k = 0; k < 4; ++k) {
            bool valid = ws_[k] > 0.0f;
            vcnt += valid ? 1u : 0u;
            int bin; bool lt;
            ghm_classify_fast(ps_[k], bin, lt);
            ghm_acc(h0, h1, valid && lt, bin);
        }
    }
    if (tid == 0) {
        for (int j2 = n4 << 2; j2 < n; ++j2) {
            bool valid = lw[j2] > 0.0f;
            vcnt += valid ? 1u : 0u;
            int bin; bool lt;
            ghm_classify_fast(pred[j2], bin, lt);
            ghm_acc(h0, h1, valid && lt, bin);
        }
    }
    ghm_reduce_commit(h0, h1, vcnt, cnt);
}

__global__ __launch_bounds__(BLK) void ghm_apply_recompute(
    const float* __restrict__ pred, const float* __restrict__ lw,
    const unsigned int* __restrict__ cnt, float* __restrict__ out, int n)
{
    const int wfi = ghm_wave_weights(cnt);

    const int tid = blockIdx.x * BLK + threadIdx.x;
    const int S   = gridDim.x * BLK;
    const int n4  = n >> 2;
    const float4* p4 = (const float4*)pred;
    const float4* w4 = (const float4*)lw;
    float4* o4       = (float4*)out;

    for (int i = tid; i < n4; i += S) {
        float4 P = p4[i];
        float4 W = w4[i];
        float ps_[4] = {P.x, P.y, P.z, P.w};
        float ws_[4] = {W.x, W.y, W.z, W.w};
        float os_[4];
#pragma unroll
        for (int k = 0; k < 4; ++k) {
            int bin; bool lt;
            ghm_classify_fast(ps_[k], bin, lt);
            bool ib = (ws_[k] > 0.0f) && lt;
            unsigned int nib = ib ? (unsigned int)bin : 15u;
            float wt = __int_as_float(
                __builtin_amdgcn_ds_bpermute((int)(nib << 2), wfi));
            os_[k] = wt * ps_[k];
        }
        float4 O;
        O.x = os_[0]; O.y = os_[1]; O.z = os_[2]; O.w = os_[3];
        o4[i] = O;
    }
    if (tid == 0 && (n & 3)) {
        unsigned int c[BINS + 1];
        for (int b = 0; b <= BINS; ++b)
            c[b] = __hip_atomic_load(&cnt[b], __ATOMIC_RELAXED,
                                     __HIP_MEMORY_SCOPE_AGENT);
        float totf = fmaxf((float)c[BINS], 1.0f);
        int nne = 0;
        for (int b = 0; b < BINS; ++b) nne += (c[b] > 0u) ? 1 : 0;
        float nf = fmaxf((float)nne, 1.0f);
        for (int j2 = n4 << 2; j2 < n; ++j2) {
            int bin; bool lt;
            ghm_classify_fast(pred[j2], bin, lt);
            bool ib = (lw[j2] > 0.0f) && lt;
            float wt = 0.0f;
            if (ib && c[bin] > 0u) {
                wt = totf / (float)c[bin];
                if (nne > 0) wt /= nf;
            }
            out[j2] = wt * pred[j2];
        }
    }
}

extern "C" void kernel_launch(void* const* d_in, const int* in_sizes, int n_in,
                              void* d_out, int out_size, void* d_ws, size_t ws_size,
                              hipStream_t stream)
{
    const float* pred = (const float*)d_in[0];
    // d_in[1] = target, unused by the math
    const float* lw   = (const float*)d_in[2];
    float* out        = (float*)d_out;
    const int n       = in_sizes[0];
    const int n4      = n >> 2;

    unsigned int* cnt = (unsigned int*)d_ws;   // [0..9]=bins, [10]=valid

    // ws is poisoned 0xAA before every call — zero the counters on-stream.
    hipMemsetAsync(d_ws, 0, (BINS + 1) * sizeof(unsigned int), stream);

    // One-time capability probe (host-only queries; capture-safe).
    static int coop_grid = -1;
    if (coop_grid < 0) {
        int dev = 0, coop = 0, cus = 0, mb = 0;
        hipGetDevice(&dev);
        hipDeviceGetAttribute(&coop, hipDeviceAttributeCooperativeLaunch, dev);
        hipDeviceGetAttribute(&cus, hipDeviceAttributeMultiprocessorCount, dev);
        if (hipOccupancyMaxActiveBlocksPerMultiprocessor(&mb, ghm_fused, BLK, 0)
            != hipSuccess) mb = 0;
        coop_grid = (coop && mb > 0 && cus > 0) ? mb * cus : 0;
    }

    // Fused path needs every float4 covered by CHUNK register slots.
    // n4 = 4.096M -> need 1000 blocks; capacity with __launch_bounds__(256,4)
    // on 256 CUs is >= 1024, so this path is taken on MI355X.
    const int need_blocks = (n4 + CHUNK * BLK - 1) / (CHUNK * BLK);
    if (n4 > 0 && need_blocks > 0 && coop_grid >= need_blocks) {
        void* args[] = {(void*)&pred, (void*)&lw, (void*)&cnt,
                        (void*)&out, (void*)&n};
        hipLaunchCooperativeKernel(reinterpret_cast<const void*>(&ghm_fused),
                                   dim3(need_blocks), dim3(BLK), args, 0u, stream);
    } else {
        const int G = 2000;
        ghm_hist<<<G, BLK, 0, stream>>>(pred, lw, cnt, n);
        ghm_apply_recompute<<<G, BLK, 0, stream>>>(pred, lw, cnt, out, n);
    }
}